// Round 7
// baseline (764.970 us; speedup 1.0000x reference)
//
#include <hip/hip_runtime.h>

#define LEAKY 0.2f
#define LN_EPS 1e-5f
#define SM_EPS 1e-16f
#define CAP 64   // max in-degree bucket; deg ~ Poisson(16), P(>64) ~ 1e-18
#define WPAD 68  // LDS row stride (floats): multiple of 4 keeps float4 aligned
#define NL_BLOCKS 2048  // blocks of k_prep doing node-linear work

// ---------------- K1+K2 fused: block-specialized prep ----------------
// blocks [0, NL_BLOCKS): xl or xr = x @ W^T + b with W in registers.
//   side = blockIdx & 1 selects {Wl->xl} or {Wr->xr}; 16 KB W staged through
//   padded LDS once per block, lane i holds row i of W in 16 float4 VGPRs.
//   Per node: 16 wave-uniform float4 x-loads (L1 broadcast) + 64 FMAs + one
//   coalesced 256B store.
// blocks [NL_BLOCKS, ...): bucket edges by dst (atomicAdd cursor + scattered
//   4B store), 1 edge/thread. deg[] pre-zeroed by hipMemsetAsync.
__global__ __launch_bounds__(256) void k_prep(
    const float* __restrict__ x,    // [N,64]
    const float* __restrict__ Wl,   // [64,64]
    const float* __restrict__ bl,   // [64]
    const float* __restrict__ Wr,   // [64,64]
    const float* __restrict__ br,   // [64]
    float* __restrict__ xl, float* __restrict__ xr,
    const int* __restrict__ ei,     // [2,E]
    int* __restrict__ deg,          // [N] (pre-zeroed)
    int* __restrict__ slot,         // [N*CAP]
    int N, int E)
{
    const int tid = threadIdx.x;

    if (blockIdx.x >= NL_BLOCKS) {
        // ---- bucket half ----
        const int e = (blockIdx.x - NL_BLOCKS) * 256 + tid;
        if (e < E) {
            const int dst = ei[E + e];
            const int pos = atomicAdd(deg + dst, 1);
            if (pos < CAP) slot[(long long)dst * CAP + pos] = e;
        }
        return;
    }

    // ---- node-linear half ----
    __shared__ __align__(16) float sW[64 * WPAD];

    const int side = blockIdx.x & 1;
    const float* __restrict__ W  = side ? Wr : Wl;
    const float* __restrict__ bv = side ? br : bl;
    float* __restrict__ dst      = side ? xr : xl;

    for (int i = tid; i < 4096; i += 256)
        sW[(i >> 6) * WPAD + (i & 63)] = W[i];
    __syncthreads();

    const int lane = tid & 63;
    float4 wq[16];
    #pragma unroll
    for (int q = 0; q < 16; ++q)
        wq[q] = *(const float4*)&sW[lane * WPAD + q * 4];
    const float bb = bv[lane];

    const int stream0 = (blockIdx.x >> 1) * 4 + (tid >> 6);
    const int nstream = (NL_BLOCKS >> 1) * 4;
    for (int n = stream0; n < N; n += nstream) {
        const float4* xrow = (const float4*)(x + (long long)n * 64);
        float a = bb;
        #pragma unroll
        for (int q = 0; q < 16; ++q) {
            const float4 xv = xrow[q];
            const float4 w  = wq[q];
            a = fmaf(xv.x, w.x, fmaf(xv.y, w.y, fmaf(xv.z, w.z, fmaf(xv.w, w.w, a))));
        }
        dst[(long long)n * 64 + lane] = a;
    }
}

// ---------------- K3: per-dst gather + softmax + aggregate + epilogue ----------------
// One 64-lane wave per destination node. R7: 16 nodes / 1024-thread block —
// per-wave code byte-identical to the proven R3 structure; only the
// node<->block mapping changed. Rationale: R3/R6 ran 25k blocks of ~1.7 us
// (76 blocks/us dispatch rate) and occupancy sat at 50% despite VGPR=48
// allowing 8 waves/SIMD -> block-dispatch churn, not resources, was the cap.
// 4x fewer, 4x longer blocks; 2 blocks/CU = 32 waves/CU possible.
// (R4 persistent-wave and R5 DPP/readlane variants both regressed.)
__global__ __launch_bounds__(1024) void k_gather(
    const int* __restrict__ ei,
    const float* __restrict__ ea,    // [E,16]
    const float* __restrict__ We,    // [64,16]
    const float* __restrict__ att,   // [64]
    const float* __restrict__ xl, const float* __restrict__ xr,
    const int* __restrict__ deg, const int* __restrict__ slot,
    const float* __restrict__ x,
    const float* __restrict__ bias, const float* __restrict__ gamma,
    const float* __restrict__ beta,
    float* __restrict__ out, int N)
{
    const int lane = threadIdx.x & 63;
    const int n = blockIdx.x * 16 + (threadIdx.x >> 6);
    if (n >= N) return;

    // per-lane constants across all edges of this node
    const float4* w4 = (const float4*)(We + lane * 16);
    const float4 w0 = w4[0], w1 = w4[1], w2 = w4[2], w3 = w4[3];
    const float attv = att[lane];
    const float xrv = xr[(long long)n * 64 + lane];

    const int d = min(deg[n], CAP);

    // wave-wide index hoist: all edge ids + src ids fetched in 2 instructions
    int veid = 0, vsrc = 0;
    if (lane < d) {
        veid = slot[(long long)n * CAP + lane];
        vsrc = ei[veid];
    }

    float acc = 0.f;   // aggregate for channel `lane`
    float ns  = 0.f;   // sum of ex for this head (replicated in 8 lanes)

    // depth-2 software pipeline over edges; explicit regs (no runtime-indexed
    // arrays -> no scratch). Stage A = edge i, stage B = edge i+1.
    float xlA = 0.f, xlB = 0.f;
    float4 a0, a1, a2, a3, b0, b1, b2, b3;
    a0 = a1 = a2 = a3 = b0 = b1 = b2 = b3 = make_float4(0.f, 0.f, 0.f, 0.f);

#define FETCH(j, XLV, E0, E1, E2, E3) do {                       \
        const int s_ = __shfl(vsrc, (j), 64);                    \
        const int e_ = __shfl(veid, (j), 64);                    \
        XLV = xl[(long long)s_ * 64 + lane];                     \
        const float4* p_ = (const float4*)(ea + (long long)e_ * 16); \
        E0 = p_[0]; E1 = p_[1]; E2 = p_[2]; E3 = p_[3];          \
    } while (0)

    if (d > 0) FETCH(0, xlA, a0, a1, a2, a3);
    if (d > 1) FETCH(1, xlB, b0, b1, b2, b3);

    for (int i = 0; i < d; ++i) {
        const float xlc = xlA;
        const float4 c0 = a0, c1 = a1, c2 = a2, c3 = a3;
        xlA = xlB; a0 = b0; a1 = b1; a2 = b2; a3 = b3;
        if (i + 2 < d) FETCH(i + 2, xlB, b0, b1, b2, b3);

        float ep = c0.x*w0.x + c0.y*w0.y + c0.z*w0.z + c0.w*w0.w
                 + c1.x*w1.x + c1.y*w1.y + c1.z*w1.z + c1.w*w1.w
                 + c2.x*w2.x + c2.y*w2.y + c2.z*w2.z + c2.w*w2.w
                 + c3.x*w3.x + c3.y*w3.y + c3.z*w3.z + c3.w*w3.w;
        float m = xlc + xrv + ep;
        m = (m > 0.f) ? m : LEAKY * m;           // leaky_relu
        float p = m * attv;
        p += __shfl_xor(p, 1, 64);               // reduce 8 lanes of this head
        p += __shfl_xor(p, 2, 64);
        p += __shfl_xor(p, 4, 64);
        const float ex = __expf(p);
        ns  += ex;
        acc = fmaf(ex, xlc, acc);
    }
#undef FETCH

    // fused epilogue
    const float a = acc / (ns + SM_EPS);
    const float hv = a + bias[lane] + x[(long long)n * 64 + lane];

    float s = hv;
    #pragma unroll
    for (int off = 32; off; off >>= 1) s += __shfl_xor(s, off, 64);
    const float mu = s * (1.f / 64.f);
    const float dd = hv - mu;
    float v = dd * dd;
    #pragma unroll
    for (int off = 32; off; off >>= 1) v += __shfl_xor(v, off, 64);
    const float var = v * (1.f / 64.f);

    float hn = dd * rsqrtf(var + LN_EPS) * gamma[lane] + beta[lane];
    out[(long long)n * 64 + lane] = (hn > 0.f) ? hn : 0.f;
}

extern "C" void kernel_launch(void* const* d_in, const int* in_sizes, int n_in,
                              void* d_out, int out_size, void* d_ws, size_t ws_size,
                              hipStream_t stream) {
    (void)n_in; (void)ws_size; (void)out_size;

    const float* x     = (const float*)d_in[0];
    const int*   ei    = (const int*)d_in[1];
    const float* ea    = (const float*)d_in[2];
    const float* Wl    = (const float*)d_in[3];
    const float* bl    = (const float*)d_in[4];
    const float* Wr    = (const float*)d_in[5];
    const float* br    = (const float*)d_in[6];
    const float* We    = (const float*)d_in[7];
    const float* att   = (const float*)d_in[8];
    const float* bias  = (const float*)d_in[9];
    const float* gamma = (const float*)d_in[10];
    const float* beta  = (const float*)d_in[11];

    const int N = in_sizes[0] / 64;   // x is [N,64]
    const int E = in_sizes[1] / 2;    // edge_index is [2,E]

    // ws: xl[N*64]f32 + xr[N*64]f32 + deg[N]i32 + slot[N*CAP]i32 = 77.2 MB
    float* w = (float*)d_ws;
    float* xl  = w;                   w += (size_t)N * 64;
    float* xr  = w;                   w += (size_t)N * 64;
    int* deg   = (int*)w;
    int* slot  = deg + N;

    float* out = (float*)d_out;

    // deg = 0 (graph-capture-safe async memset; 400 KB, ~negligible)
    hipMemsetAsync(deg, 0, (size_t)N * sizeof(int), stream);

    // fused prep: 2048 linear blocks + ceil(E/256) bucket blocks
    const int nbBucket = (E + 255) / 256;
    k_prep<<<NL_BLOCKS + nbBucket, 256, 0, stream>>>(
        x, Wl, bl, Wr, br, xl, xr, ei, deg, slot, N, E);

    // 16 nodes per 1024-thread block: 6250 blocks
    k_gather<<<(N + 15) / 16, 1024, 0, stream>>>(
        ei, ea, We, att, xl, xr, deg, slot, x, bias, gamma, beta, out, N);
}

// Round 8
// 629.724 us; speedup vs baseline: 1.2148x; 1.2148x over previous
//
#include <hip/hip_runtime.h>

#define LEAKY 0.2f
#define LN_EPS 1e-5f
#define SM_EPS 1e-16f
#define CAP 64     // max in-degree bucket; deg ~ Poisson(16), P(>64) ~ 1e-18
#define WPAD 68    // LDS row stride (floats): multiple of 4 keeps float4 aligned

// ---- binned bucketing geometry ----
#define BIN_SHIFT 8          // 256 dsts per bin
#define MAXBINS   448        // supports N <= 114688; runtime fallback otherwise
#define CHUNK_A   7168       // edges per k_binA block (LDS ord = 56 KB)
#define BCAP      5120       // per-bin capacity; bin load ~Poisson(4096), 16 sigma margin

// ---------------- K1: xl or xr = x @ W^T + b, W held in registers ----------------
// side = blockIdx.x & 1 selects {Wl->xl} or {Wr->xr}. 16 KB W staged through
// padded LDS once per block; lane i owns row i of W in 16 float4 VGPRs.
// Per node: 16 wave-uniform float4 x-loads (L1 broadcast) + 64 FMAs + one
// coalesced 256B store. (deg zeroing moved to hipMemsetAsync.)
__global__ __launch_bounds__(256) void k_node_linear(
    const float* __restrict__ x,    // [N,64]
    const float* __restrict__ Wl,   // [64,64]
    const float* __restrict__ bl,   // [64]
    const float* __restrict__ Wr,   // [64,64]
    const float* __restrict__ br,   // [64]
    float* __restrict__ xl, float* __restrict__ xr, int N)
{
    __shared__ __align__(16) float sW[64 * WPAD];

    const int tid = threadIdx.x;
    const int side = blockIdx.x & 1;
    const float* __restrict__ W  = side ? Wr : Wl;
    const float* __restrict__ bv = side ? br : bl;
    float* __restrict__ dst      = side ? xr : xl;

    for (int i = tid; i < 4096; i += 256)
        sW[(i >> 6) * WPAD + (i & 63)] = W[i];
    __syncthreads();

    const int lane = tid & 63;
    float4 wq[16];
    #pragma unroll
    for (int q = 0; q < 16; ++q)
        wq[q] = *(const float4*)&sW[lane * WPAD + q * 4];
    const float bb = bv[lane];

    const int stream0 = (blockIdx.x >> 1) * 4 + (tid >> 6);
    const int nstream = (gridDim.x >> 1) * 4;
    for (int n = stream0; n < N; n += nstream) {
        const float4* xrow = (const float4*)(x + (long long)n * 64);
        float a = bb;
        #pragma unroll
        for (int q = 0; q < 16; ++q) {
            const float4 xv = xrow[q];
            const float4 w  = wq[q];
            a = fmaf(xv.x, w.x, fmaf(xv.y, w.y, fmaf(xv.z, w.z, fmaf(xv.w, w.w, a))));
        }
        dst[(long long)n * 64 + lane] = a;
    }
}

// ---------------- K2 legacy: direct scattered bucket (ws-fallback only) ----------------
__global__ __launch_bounds__(256) void k_bucket(
    const int* __restrict__ ei, int* __restrict__ deg,
    int* __restrict__ slot, int E)
{
    const int e = blockIdx.x * 256 + threadIdx.x;
    if (e >= E) return;
    const int dst = ei[E + e];
    const int pos = atomicAdd(deg + dst, 1);
    if (pos < CAP) slot[(long long)dst * CAP + pos] = e;
}

// ---------------- K2a: coarse binning via LDS counting sort ----------------
// Replaces 3.2M scattered 4B global ops (atomic+store per edge, ~240 us at
// measured ~15 Gop/s scattered-dword throughput) with: LDS counting sort by
// bin (dst>>8), ONE global atomicAdd per (block,bin) (~77k total), and a
// bin-ordered coalesced 8B copy-out.
__global__ __launch_bounds__(256) void k_binA(
    const int* __restrict__ ei,      // [2,E]
    int* __restrict__ binCnt,        // [nbins] (pre-zeroed)
    int2* __restrict__ binArr,       // [nbins*BCAP] (e,dst)
    int E, int nbins)
{
    __shared__ int2 ord[CHUNK_A];
    __shared__ int cnt[MAXBINS], offs[MAXBINS], cur[MAXBINS], resB[MAXBINS];

    const int tid  = threadIdx.x;
    const int lane = tid & 63;
    const int ebase = blockIdx.x * CHUNK_A;
    const int nE = (E - ebase < CHUNK_A) ? (E - ebase) : CHUNK_A;
    const int* __restrict__ dstp = ei + E + ebase;

    for (int b = tid; b < MAXBINS; b += 256) { cnt[b] = 0; cur[b] = 0; }
    __syncthreads();

    // p1: count per bin
    for (int i = tid; i < nE; i += 256)
        atomicAdd(&cnt[dstp[i] >> BIN_SHIFT], 1);
    __syncthreads();

    // exclusive scan over MAXBINS (wave 0: 7 segments of 64, shfl_up scan)
    if (tid < 64) {
        int carry = 0;
        #pragma unroll
        for (int seg = 0; seg < MAXBINS / 64; ++seg) {
            const int v = cnt[seg * 64 + lane];
            int s = v;
            #pragma unroll
            for (int off = 1; off < 64; off <<= 1) {
                const int t = __shfl_up(s, off, 64);
                if (lane >= off) s += t;
            }
            offs[seg * 64 + lane] = carry + s - v;
            carry += __shfl(s, 63, 64);
        }
    }
    __syncthreads();

    // p2: place (e,dst) bin-ordered in LDS
    for (int i = tid; i < nE; i += 256) {
        const int d = dstp[i];
        const int b = d >> BIN_SHIFT;
        const int pos = atomicAdd(&cur[b], 1);
        ord[offs[b] + pos] = make_int2(ebase + i, d);
    }
    __syncthreads();

    // reserve global ranges (one atomic per non-empty bin per block)
    for (int b = tid; b < nbins; b += 256) {
        const int c = cnt[b];
        resB[b] = c ? atomicAdd(&binCnt[b], c) : 0;
    }
    __syncthreads();

    // coalesced copy-out: consecutive i are mostly same-bin runs
    for (int i = tid; i < nE; i += 256) {
        const int2 p = ord[i];
        const int b = p.y >> BIN_SHIFT;
        const int k = resB[b] + (i - offs[b]);
        if (k < BCAP) binArr[(long long)b * BCAP + k] = p;
    }
}

// ---------------- K2b: per-bin exact bucketing, coalesced deg/slot out ----------------
__global__ __launch_bounds__(256) void k_binB(
    const int* __restrict__ binCnt,
    const int2* __restrict__ binArr,
    int* __restrict__ deg,           // [N]
    int* __restrict__ slot,          // [N*CAP]
    int N)
{
    __shared__ int ord2[BCAP];
    __shared__ int cnt2[256], offs2[256], cur2[256];

    const int b = blockIdx.x;
    const int tid  = threadIdx.x;
    const int lane = tid & 63;
    const int dst0 = b << BIN_SHIFT;
    int nb = binCnt[b];
    if (nb > BCAP) nb = BCAP;
    const int2* __restrict__ src = binArr + (long long)b * BCAP;

    cnt2[tid] = 0; cur2[tid] = 0;
    __syncthreads();

    for (int i = tid; i < nb; i += 256)
        atomicAdd(&cnt2[src[i].y - dst0], 1);
    __syncthreads();

    if (tid < 64) {
        int carry = 0;
        #pragma unroll
        for (int seg = 0; seg < 4; ++seg) {
            const int v = cnt2[seg * 64 + lane];
            int s = v;
            #pragma unroll
            for (int off = 1; off < 64; off <<= 1) {
                const int t = __shfl_up(s, off, 64);
                if (lane >= off) s += t;
            }
            offs2[seg * 64 + lane] = carry + s - v;
            carry += __shfl(s, 63, 64);
        }
    }
    __syncthreads();

    for (int i = tid; i < nb; i += 256) {
        const int2 p = src[i];
        const int d = p.y - dst0;
        const int pos = atomicAdd(&cur2[d], 1);
        ord2[offs2[d] + pos] = p.x;
    }
    __syncthreads();

    const int nd = (N - dst0 < 256) ? (N - dst0) : 256;
    if (tid < nd) deg[dst0 + tid] = cnt2[tid];

    // one wave per dst row: <=64 x 4B contiguous burst per row
    const int wv = tid >> 6;
    for (int d = wv; d < nd; d += 4) {
        int c = cnt2[d];
        if (c > CAP) c = CAP;
        if (lane < c) slot[(long long)(dst0 + d) * CAP + lane] = ord2[offs2[d] + lane];
    }
}

// ---------------- K3: per-dst gather + softmax + aggregate + epilogue ----------------
// One 64-lane wave per destination node (4 nodes / 256-thread block).
// Wave-wide index hoist; depth-2 explicit-reg pipeline; fused epilogue.
// FROZEN at the proven R3 structure (persistent/DPP/1024-block variants all
// regressed: R4/R5/R7).
__global__ __launch_bounds__(256) void k_gather(
    const int* __restrict__ ei,
    const float* __restrict__ ea,    // [E,16]
    const float* __restrict__ We,    // [64,16]
    const float* __restrict__ att,   // [64]
    const float* __restrict__ xl, const float* __restrict__ xr,
    const int* __restrict__ deg, const int* __restrict__ slot,
    const float* __restrict__ x,
    const float* __restrict__ bias, const float* __restrict__ gamma,
    const float* __restrict__ beta,
    float* __restrict__ out, int N)
{
    const int lane = threadIdx.x & 63;
    const int n = blockIdx.x * 4 + (threadIdx.x >> 6);
    if (n >= N) return;

    const float4* w4 = (const float4*)(We + lane * 16);
    const float4 w0 = w4[0], w1 = w4[1], w2 = w4[2], w3 = w4[3];
    const float attv = att[lane];
    const float xrv = xr[(long long)n * 64 + lane];

    const int d = min(deg[n], CAP);

    int veid = 0, vsrc = 0;
    if (lane < d) {
        veid = slot[(long long)n * CAP + lane];
        vsrc = ei[veid];
    }

    float acc = 0.f;
    float ns  = 0.f;

    float xlA = 0.f, xlB = 0.f;
    float4 a0, a1, a2, a3, b0, b1, b2, b3;
    a0 = a1 = a2 = a3 = b0 = b1 = b2 = b3 = make_float4(0.f, 0.f, 0.f, 0.f);

#define FETCH(j, XLV, E0, E1, E2, E3) do {                       \
        const int s_ = __shfl(vsrc, (j), 64);                    \
        const int e_ = __shfl(veid, (j), 64);                    \
        XLV = xl[(long long)s_ * 64 + lane];                     \
        const float4* p_ = (const float4*)(ea + (long long)e_ * 16); \
        E0 = p_[0]; E1 = p_[1]; E2 = p_[2]; E3 = p_[3];          \
    } while (0)

    if (d > 0) FETCH(0, xlA, a0, a1, a2, a3);
    if (d > 1) FETCH(1, xlB, b0, b1, b2, b3);

    for (int i = 0; i < d; ++i) {
        const float xlc = xlA;
        const float4 c0 = a0, c1 = a1, c2 = a2, c3 = a3;
        xlA = xlB; a0 = b0; a1 = b1; a2 = b2; a3 = b3;
        if (i + 2 < d) FETCH(i + 2, xlB, b0, b1, b2, b3);

        float ep = c0.x*w0.x + c0.y*w0.y + c0.z*w0.z + c0.w*w0.w
                 + c1.x*w1.x + c1.y*w1.y + c1.z*w1.z + c1.w*w1.w
                 + c2.x*w2.x + c2.y*w2.y + c2.z*w2.z + c2.w*w2.w
                 + c3.x*w3.x + c3.y*w3.y + c3.z*w3.z + c3.w*w3.w;
        float m = xlc + xrv + ep;
        m = (m > 0.f) ? m : LEAKY * m;           // leaky_relu
        float p = m * attv;
        p += __shfl_xor(p, 1, 64);
        p += __shfl_xor(p, 2, 64);
        p += __shfl_xor(p, 4, 64);
        const float ex = __expf(p);
        ns  += ex;
        acc = fmaf(ex, xlc, acc);
    }
#undef FETCH

    const float a = acc / (ns + SM_EPS);
    const float hv = a + bias[lane] + x[(long long)n * 64 + lane];

    float s = hv;
    #pragma unroll
    for (int off = 32; off; off >>= 1) s += __shfl_xor(s, off, 64);
    const float mu = s * (1.f / 64.f);
    const float dd = hv - mu;
    float v = dd * dd;
    #pragma unroll
    for (int off = 32; off; off >>= 1) v += __shfl_xor(v, off, 64);
    const float var = v * (1.f / 64.f);

    float hn = dd * rsqrtf(var + LN_EPS) * gamma[lane] + beta[lane];
    out[(long long)n * 64 + lane] = (hn > 0.f) ? hn : 0.f;
}

extern "C" void kernel_launch(void* const* d_in, const int* in_sizes, int n_in,
                              void* d_out, int out_size, void* d_ws, size_t ws_size,
                              hipStream_t stream) {
    (void)n_in; (void)out_size;

    const float* x     = (const float*)d_in[0];
    const int*   ei    = (const int*)d_in[1];
    const float* ea    = (const float*)d_in[2];
    const float* Wl    = (const float*)d_in[3];
    const float* bl    = (const float*)d_in[4];
    const float* Wr    = (const float*)d_in[5];
    const float* br    = (const float*)d_in[6];
    const float* We    = (const float*)d_in[7];
    const float* att   = (const float*)d_in[8];
    const float* bias  = (const float*)d_in[9];
    const float* gamma = (const float*)d_in[10];
    const float* beta  = (const float*)d_in[11];

    const int N = in_sizes[0] / 64;   // x is [N,64]
    const int E = in_sizes[1] / 2;    // edge_index is [2,E]
    const int nbins = (N + (1 << BIN_SHIFT) - 1) >> BIN_SHIFT;

    // ws layout: xl, xr, deg[N], binCnt[MAXBINS], slot[N*CAP], binArr[nbins*BCAP] int2
    float* w = (float*)d_ws;
    float* xl   = w;                      w += (size_t)N * 64;
    float* xr   = w;                      w += (size_t)N * 64;
    int* deg    = (int*)w;
    int* binCnt = deg + N;
    int* slot   = binCnt + MAXBINS;
    int2* binArr = (int2*)(slot + (size_t)N * CAP);
    const size_t needed = ((char*)(binArr + (size_t)nbins * BCAP)) - (char*)d_ws;

    float* out = (float*)d_out;

    const bool binned = (nbins <= MAXBINS) && (ws_size >= needed);

    // zero deg + binCnt in one memset (contiguous)
    hipMemsetAsync(deg, 0, ((size_t)N + MAXBINS) * sizeof(int), stream);

    k_node_linear<<<2048, 256, 0, stream>>>(x, Wl, bl, Wr, br, xl, xr, N);

    if (binned) {
        const int nbA = (E + CHUNK_A - 1) / CHUNK_A;
        k_binA<<<nbA, 256, 0, stream>>>(ei, binCnt, binArr, E, nbins);
        k_binB<<<nbins, 256, 0, stream>>>(binCnt, binArr, deg, slot, N);
    } else {
        k_bucket<<<(E + 255) / 256, 256, 0, stream>>>(ei, deg, slot, E);
    }

    k_gather<<<(N + 3) / 4, 256, 0, stream>>>(
        ei, ea, We, att, xl, xr, deg, slot, x, bias, gamma, beta, out, N);
}